// Round 13
// baseline (120.200 us; speedup 1.0000x reference)
//
#include <hip/hip_runtime.h>

// ConvTranspose3d(3->16,k=3,s=2,p=1) + per-channel BN-norm + 2x avgpool2, fully fused.
// Identity 1: pooled output = stride-2 3^3 conv of x with collapsed kernel G.
// Identity 2: sum(y), sum(y^2) via x-autocorrelation at 27 lags + inclusion-exclusion
// boundary corrections (faces/edges/corners).
// R13: autocorr pass-split across blocks (one (dd,dh) pass per block, 4608 blocks),
// rbuf aliased into xs (44KB LDS -> 3 blocks/CU); pooled conv (raw) merged into the
// mega dispatch with per-block G prep; float4 norm pass last. 4 launches.

#define I3 32768
#define NS 98304              // n stride in x = 3*32768
#define COUNT_Y 8001504.0f    // 32*63^3
#define POOL3 3375
#define TOTAL_OUT 1728000

// ws layout (floats)
#define WS_A3P  0        // 4608*18 = 82944   [s512][pass][18]
#define WS_X3P  82944    // 512*3   = 1536
#define WS_A2P  84480    // 486*32  = 15552
#define WS_X2P  100032   // 18*32   = 576
#define WS_A1   100608   // 324
#define WS_X1   100932   // 36
#define WS_A3R  100968   // 246 (ordered A3 [243] + X3 [3])
#define WS_AB   101214   // 32   -> ~405 KB

// mega smem: 11016 floats = 44,064 B  -> 3 blocks/CU
// autocorr: XS [3][6][34][16]=9792 @0, HLO 612 @9792, HHI 612 @10404
//           rbuf 256*20=5120 aliased @0 (after xs reads done), RB2 160 @5120,
//           redX 12 @5280
// pooled:   gsub 648 @0 ; faces/edges: PL 3168 @0
#define SMF 11016

__device__ __forceinline__ float4 add4(float4 a, float4 b) {
    return make_float4(a.x + b.x, a.y + b.y, a.z + b.z, a.w + b.w);
}

__global__ __launch_bounds__(256, 3) void mega_k(
    const float* __restrict__ x, const float* __restrict__ w,
    float* __restrict__ A3p, float* __restrict__ X3p,
    float* __restrict__ A2P, float* __restrict__ X2P,
    float* __restrict__ A1, float* __restrict__ X1,
    float* __restrict__ out)
{
    const int b = blockIdx.x;
    const int tid = threadIdx.x;
    __shared__ float smem[SMF];

    if (b < 4608) {
        // ======== autocorr: one (dd,dh) pass per block ========
        const int n = b & 31;
        const int t = b >> 5;               // 0..143
        const int pass = t % 9;             // ddh
        const int sw = t / 9;               // 0..15 slab-half
        const int dblk = sw >> 1, whalf = sw & 1;
        const int d0 = dblk * 4, w0 = whalf * 16;
        const int s512 = sw * 32 + n;
        const int dd = pass / 3 - 1, dh = pass % 3 - 1;
        const int dsub = tid >> 7;
        const int h    = (tid >> 2) & 31;
        const int w4   = tid & 3;
        const int wave = tid >> 6, lane = tid & 63;

        #define XS(ci,dp,hh,ww)  smem[(((ci)*6+(dp))*34+(hh))*16+(ww)]
        #define HLO(ci,dp,hh)    smem[9792 + ((ci)*6+(dp))*34+(hh)]
        #define HHI(ci,dp,hh)    smem[10404 + ((ci)*6+(dp))*34+(hh)]

        for (int i = tid; i < SMF; i += 256) smem[i] = 0.f;
        __syncthreads();

        for (int i = tid; i < 2304; i += 256) {       // 3ci*6dp*32hh*4chunks
            const int c4 = i & 3, hh = (i >> 2) & 31, cp = i >> 7;
            const int dp = cp % 6, ci = cp / 6;
            const int d = d0 - 1 + dp;
            if ((unsigned)d < 32u) {
                const float4 f = *reinterpret_cast<const float4*>(
                    x + (size_t)n * NS + ci * I3 + d * 1024 + hh * 32 + w0 + c4 * 4);
                *reinterpret_cast<float4*>(&XS(ci, dp, hh + 1, c4 * 4)) = f;
            }
        }
        for (int i = tid; i < 1152; i += 256) {       // halo columns
            const int side = i & 1, hh = (i >> 1) & 31, cp = i >> 6;
            const int dp = cp % 6, ci = cp / 6;
            const int d = d0 - 1 + dp;
            const int gw = side ? (w0 + 16) : (w0 - 1);
            if ((unsigned)d < 32u && (unsigned)gw < 32u) {
                const float v = x[(size_t)n * NS + ci * I3 + d * 1024 + hh * 32 + gw];
                if (side) HHI(ci, dp, hh + 1) = v; else HLO(ci, dp, hh + 1) = v;
            }
        }
        __syncthreads();

        float4 ov[2][3];
        #pragma unroll
        for (int dl = 0; dl < 2; ++dl) {
            const int dp = 1 + dsub * 2 + dl;
            #pragma unroll
            for (int ci = 0; ci < 3; ++ci)
                ov[dl][ci] = *reinterpret_cast<const float4*>(&XS(ci, dp, h + 1, w4 * 4));
        }
        float sx[3] = {0.f, 0.f, 0.f};
        if (pass == 4) {
            #pragma unroll
            for (int ci = 0; ci < 3; ++ci)
                sx[ci] = ov[0][ci].x + ov[0][ci].y + ov[0][ci].z + ov[0][ci].w +
                         ov[1][ci].x + ov[1][ci].y + ov[1][ci].z + ov[1][ci].w;
        }

        float acc[18];
        #pragma unroll
        for (int j = 0; j < 18; ++j) acc[j] = 0.f;

        #pragma unroll
        for (int dl = 0; dl < 2; ++dl) {
            const int dp = 1 + dsub * 2 + dl;
            const int dpn = dp + dd, hn = h + 1 + dh;
            #pragma unroll
            for (int cj = 0; cj < 3; ++cj) {
                const float4 bv = *reinterpret_cast<const float4*>(&XS(cj, dpn, hn, w4 * 4));
                float nxt = __shfl(bv.x, lane + 1, 64);
                float prv = __shfl(bv.w, lane - 1, 64);
                if (w4 == 3) nxt = HHI(cj, dpn, hn);
                if (w4 == 0) prv = HLO(cj, dpn, hn);
                // unordered pairs ci<=cj: q(0,0)=0 q(0,1)=1 q(0,2)=2 q(1,1)=3 q(1,2)=4 q(2,2)=5
                #pragma unroll
                for (int ci = 0; ci <= cj; ++ci) {
                    const int q = (cj == 0) ? 0 : (cj == 1 ? (ci == 0 ? 1 : 3)
                                                            : (ci == 0 ? 2 : (ci == 1 ? 4 : 5)));
                    const int p3 = q * 3;
                    const float4 o = ov[dl][ci];
                    acc[p3 + 0] = fmaf(o.x, prv,  acc[p3 + 0]);
                    acc[p3 + 0] = fmaf(o.y, bv.x, acc[p3 + 0]);
                    acc[p3 + 0] = fmaf(o.z, bv.y, acc[p3 + 0]);
                    acc[p3 + 0] = fmaf(o.w, bv.z, acc[p3 + 0]);
                    acc[p3 + 1] = fmaf(o.x, bv.x, acc[p3 + 1]);
                    acc[p3 + 1] = fmaf(o.y, bv.y, acc[p3 + 1]);
                    acc[p3 + 1] = fmaf(o.z, bv.z, acc[p3 + 1]);
                    acc[p3 + 1] = fmaf(o.w, bv.w, acc[p3 + 1]);
                    acc[p3 + 2] = fmaf(o.x, bv.y, acc[p3 + 2]);
                    acc[p3 + 2] = fmaf(o.y, bv.z, acc[p3 + 2]);
                    acc[p3 + 2] = fmaf(o.z, bv.w, acc[p3 + 2]);
                    acc[p3 + 2] = fmaf(o.w, nxt,  acc[p3 + 2]);
                }
            }
        }

        __syncthreads();   // all xs/halo reads done -> safe to alias rbuf over xs
        {
            float4* rb = reinterpret_cast<float4*>(&smem[tid * 20]);
            rb[0] = make_float4(acc[0],  acc[1],  acc[2],  acc[3]);
            rb[1] = make_float4(acc[4],  acc[5],  acc[6],  acc[7]);
            rb[2] = make_float4(acc[8],  acc[9],  acc[10], acc[11]);
            rb[3] = make_float4(acc[12], acc[13], acc[14], acc[15]);
            rb[4] = make_float4(acc[16], acc[17], 0.f, 0.f);
        }
        if (pass == 4) {
            #pragma unroll
            for (int m = 1; m < 64; m <<= 1) {
                sx[0] += __shfl_xor(sx[0], m, 64);
                sx[1] += __shfl_xor(sx[1], m, 64);
                sx[2] += __shfl_xor(sx[2], m, 64);
            }
            if (lane == 0) {
                smem[5280 + wave * 3 + 0] = sx[0];
                smem[5280 + wave * 3 + 1] = sx[1];
                smem[5280 + wave * 3 + 2] = sx[2];
            }
        }
        __syncthreads();
        if (tid < 40) {
            const int j4 = tid % 5, rblk = tid / 5;
            float4 s = make_float4(0.f, 0.f, 0.f, 0.f);
            #pragma unroll
            for (int k = 0; k < 32; ++k) {
                const int r = rblk + k * 8;
                s = add4(s, *reinterpret_cast<const float4*>(&smem[r * 20 + j4 * 4]));
            }
            *reinterpret_cast<float4*>(&smem[5120 + tid * 4]) = s;
        }
        __syncthreads();
        if (tid < 18) {
            float s = 0.f;
            #pragma unroll
            for (int rblk = 0; rblk < 8; ++rblk) s += smem[5120 + rblk * 20 + tid];
            A3p[(size_t)(s512 * 9 + pass) * 18 + tid] = s;
        }
        if (pass == 4 && tid >= 18 && tid < 21) {
            const int ci = tid - 18;
            X3p[s512 * 3 + ci] = smem[5280 + ci] + smem[5280 + 3 + ci] +
                                 smem[5280 + 6 + ci] + smem[5280 + 9 + ci];
        }
        return;
    }

    if (b < 5568) {
        // ======== pooled conv (raw sums), G computed in-block ========
        const int t = b - 4608;
        const int pdcoh = t >> 5, n = t & 31;
        const int pd = pdcoh >> 1, coh = pdcoh & 1;

        // gsub[ci][c8][27] at smem[0..648)
        for (int idx = tid; idx < 648; idx += 256) {
            const int ci = idx / 216, rem = idx % 216, c8 = rem / 27, j = rem % 27;
            const int jd = j / 9, jh = (j / 3) % 3, jw = j % 3;
            const int SLEN[3] = {2, 3, 1};
            const int SK[3][3] = {{1, 2, 0}, {0, 1, 2}, {0, 0, 0}};
            const float* wp = w + (ci * 16 + coh * 8 + c8) * 27;
            float s = 0.f;
            for (int a = 0; a < SLEN[jd]; ++a)
                for (int bq = 0; bq < SLEN[jh]; ++bq)
                    for (int c = 0; c < SLEN[jw]; ++c)
                        s += wp[SK[jd][a] * 9 + SK[jh][bq] * 3 + SK[jw][c]];
            smem[idx] = s;
        }
        __syncthreads();
        if (tid >= 225) return;

        const int ph = tid / 15, pw = tid % 15;
        const float* xn = x + (size_t)n * NS;
        float acc[8] = {};
        #pragma unroll
        for (int ci = 0; ci < 3; ++ci) {
            float xl[27];
            const float* xc = xn + ci * I3 + (2 * pd) * 1024 + (2 * ph) * 32 + 2 * pw;
            #pragma unroll
            for (int jd = 0; jd < 3; ++jd)
                #pragma unroll
                for (int jh = 0; jh < 3; ++jh) {
                    const float* r = xc + jd * 1024 + jh * 32;
                    const float2 f2 = *reinterpret_cast<const float2*>(r);
                    xl[jd * 9 + jh * 3 + 0] = f2.x;
                    xl[jd * 9 + jh * 3 + 1] = f2.y;
                    xl[jd * 9 + jh * 3 + 2] = r[2];
                }
            #pragma unroll
            for (int c8 = 0; c8 < 8; ++c8) {
                const float* gp = &smem[(ci * 8 + c8) * 27];
                #pragma unroll
                for (int j = 0; j < 27; ++j)
                    acc[c8] = fmaf(gp[j], xl[j], acc[c8]);
            }
        }
        const int ob = (n * 16 + coh * 8) * POOL3 + pd * 225 + ph * 15 + pw;
        #pragma unroll
        for (int c8 = 0; c8 < 8; ++c8) out[ob + c8 * POOL3] = acc[c8];
        return;
    }

    #define PL(ci,u,v) smem[((ci)*32+(u))*33+(v)]
    if (b < 5760) {
        // ======== faces ========
        const int t = b - 5568;
        const int f = t >> 5, n = t & 31;
        const int s = f >> 1, e = (f & 1) ? 31 : 0;
        int su, sv, off;
        if (s == 0)      { su = 32;   sv = 1;  off = e * 1024; }
        else if (s == 1) { su = 1024; sv = 1;  off = e * 32;   }
        else             { su = 1024; sv = 32; off = e;        }
        const float* xb = x + (size_t)n * NS + off;
        for (int idx = tid; idx < 3072; idx += 256) {
            const int ci = idx >> 10, r = idx & 1023, u = r >> 5, v = r & 31;
            PL(ci, u, v) = xb[ci * I3 + u * su + v * sv];
        }
        __syncthreads();
        const int grp = tid >> 5, u = tid & 31;
        #pragma unroll 1
        for (int j = grp; j < 84; j += 8) {
            float t2 = 0.f;
            if (j < 81) {
                const int p = j / 9, lag = j % 9;
                const int du = lag / 3 - 1, dv = lag % 3 - 1;
                const int ci = p / 3, cj = p % 3;
                const int un = u + du;
                if ((unsigned)un < 32u) {
                    const int vlo = (dv == -1) ? 1 : 0, vhi = (dv == 1) ? 30 : 31;
                    const float* ro = &PL(ci, u, 0);
                    const float* rn = &PL(cj, un, dv);
                    for (int v = vlo; v <= vhi; ++v) t2 = fmaf(ro[v], rn[v], t2);
                }
            } else {
                const int ci = j - 81;
                for (int v = 0; v < 32; ++v) t2 += PL(ci, u, v);
            }
            #pragma unroll
            for (int m = 1; m < 32; m <<= 1) t2 += __shfl_xor(t2, m, 32);
            if (u == 0) {
                if (j < 81) A2P[(f * 81 + j) * 32 + n] = t2;
                else        X2P[(f * 3 + (j - 81)) * 32 + n] = t2;
            }
        }
        return;
    }

    // ======== edges ========
    {
        const int e12 = b - 5760;
        const int dp = e12 >> 2;
        const int e1 = ((e12 >> 1) & 1) ? 31 : 0, e2 = (e12 & 1) ? 31 : 0;
        int st, off;
        if (dp == 0)      { st = 1;    off = e1 * 1024 + e2 * 32; }
        else if (dp == 1) { st = 32;   off = e1 * 1024 + e2;      }
        else              { st = 1024; off = e1 * 32 + e2;        }
        for (int idx = tid; idx < 3072; idx += 256) {
            const int ci = idx >> 10, r = idx & 1023, n = r >> 5, v = r & 31;
            PL(ci, n, v) = x[(size_t)n * NS + ci * I3 + off + v * st];
        }
        __syncthreads();
        const int grp = tid >> 5, n2 = tid & 31;
        #pragma unroll 1
        for (int j = grp; j < 30; j += 8) {
            float t = 0.f;
            if (j < 27) {
                const int p = j / 3, dt = j % 3 - 1;
                const int ci = p / 3, cj = p % 3;
                const int vlo = (dt == -1) ? 1 : 0, vhi = (dt == 1) ? 30 : 31;
                const float* ro = &PL(ci, n2, 0);
                const float* rn = &PL(cj, n2, dt);
                for (int v = vlo; v <= vhi; ++v) t = fmaf(ro[v], rn[v], t);
            } else {
                const int ci = j - 27;
                for (int v = 0; v < 32; ++v) t += PL(ci, n2, v);
            }
            #pragma unroll
            for (int m = 1; m < 32; m <<= 1) t += __shfl_xor(t, m, 32);
            if (n2 == 0) {
                if (j < 27) A1[e12 * 27 + j] = t;
                else        X1[e12 * 3 + (j - 27)] = t;
            }
        }
    }
}

// ---------- reduce + expand symmetric A3 -> ordered 243 (+ X3) ----------
__global__ __launch_bounds__(256) void reduce_A3(
    const float* __restrict__ A3p, const float* __restrict__ X3p,
    float* __restrict__ A3r) {
    const int wv = blockIdx.x * 4 + (threadIdx.x >> 6);  // 0..247
    const int lane = threadIdx.x & 63;
    float s = 0.f;
    if (wv < 243) {
        const int p = wv / 27, lag = wv % 27;
        const int ci = p / 3, cj = p % 3;
        int q, l2;
        if (ci <= cj) {
            q = (ci == 0) ? cj : (ci == 1 ? 2 + cj : 5);
            l2 = lag;
        } else {
            q = (cj == 0) ? ci : 4;
            l2 = 26 - lag;
        }
        const int pass = l2 / 3, dw = l2 % 3;
        const int off = pass * 18 + q * 3 + dw;
        #pragma unroll
        for (int k = 0; k < 8; ++k)
            s += A3p[(size_t)(lane * 8 + k) * 162 + off];
    } else if (wv < 246) {
        const int ci = wv - 243;
        #pragma unroll
        for (int k = 0; k < 8; ++k) s += X3p[(lane * 8 + k) * 3 + ci];
    }
    #pragma unroll
    for (int m = 1; m < 64; m <<= 1) s += __shfl_xor(s, m, 64);
    if (lane == 0 && wv < 246) A3r[wv] = s;
}

// ---------- finalize: combine A's with weight-pair sums -> ab ----------
__global__ __launch_bounds__(256) void finalize2(
    const float* __restrict__ x, const float* __restrict__ w,
    const float* __restrict__ gamma, const float* __restrict__ beta,
    const float* __restrict__ ws, float* __restrict__ ab) {
    const int tid = threadIdx.x;
    __shared__ float lw[1296];
    __shared__ float lA3[243], lX3[3], lA2[486], lX2[18], lA1[324], lX1[36];
    __shared__ float lxc[8][3][32];
    __shared__ float lA0[72], lX0[24];
    __shared__ float red2[144], red1[48];

    for (int i = tid; i < 1296; i += 256) lw[i] = w[i];
    if (tid < 243) lA3[tid] = ws[WS_A3R + tid];
    if (tid >= 243 && tid < 246) lX3[tid - 243] = ws[WS_A3R + tid];
    for (int i = tid; i < 486; i += 256) {
        const float* p = ws + WS_A2P + i * 32;
        float s = 0.f;
        #pragma unroll
        for (int nn = 0; nn < 32; ++nn) s += p[nn];
        lA2[i] = s;
    }
    if (tid < 18) {
        const float* p = ws + WS_X2P + tid * 32;
        float s = 0.f;
        for (int nn = 0; nn < 32; ++nn) s += p[nn];
        lX2[tid] = s;
    }
    for (int i = tid; i < 324; i += 256) lA1[i] = ws[WS_A1 + i];
    if (tid < 36) lX1[tid] = ws[WS_X1 + tid];
    for (int i = tid; i < 768; i += 256) {
        const int c = i / 96, ci = (i / 32) % 3, nn = i % 32;
        const int off = (((c >> 2) & 1) ? 31 : 0) * 1024 +
                        (((c >> 1) & 1) ? 31 : 0) * 32 + ((c & 1) ? 31 : 0);
        lxc[c][ci][nn] = x[(size_t)nn * NS + ci * I3 + off];
    }
    __syncthreads();
    if (tid < 72) {
        const int c = tid / 9, p = tid % 9, ci = p / 3, cj = p % 3;
        float s = 0.f;
        for (int nn = 0; nn < 32; ++nn) s += lxc[c][ci][nn] * lxc[c][cj][nn];
        lA0[tid] = s;
    }
    if (tid >= 72 && tid < 96) {
        const int t = tid - 72, c = t / 3, ci = t % 3;
        float s = 0.f;
        for (int nn = 0; nn < 32; ++nn) s += lxc[c][ci][nn];
        lX0[t] = s;
    }
    __syncthreads();

    const int KPn[3] = {1, 3, 1};
    const int KPa[3][3] = {{0, 0, 0}, {0, 1, 2}, {2, 0, 0}};
    const int KPb[3][3] = {{2, 0, 0}, {0, 1, 2}, {0, 0, 0}};

    if (tid < 144) {
        const int co = tid / 9, p = tid % 9, ci = p / 3, cj = p % 3;
        const float* wi = lw + (ci * 16 + co) * 27;
        const float* wj = lw + (cj * 16 + co) * 27;
        float tot = 0.f;
        for (int dd = 0; dd < 3; ++dd)
            for (int dh = 0; dh < 3; ++dh)
                for (int dw = 0; dw < 3; ++dw) {
                    float sw = 0.f;
                    for (int a = 0; a < KPn[dd]; ++a)
                        for (int b = 0; b < KPn[dh]; ++b)
                            for (int c = 0; c < KPn[dw]; ++c)
                                sw += wi[KPa[dd][a] * 9 + KPa[dh][b] * 3 + KPa[dw][c]] *
                                      wj[KPb[dd][a] * 9 + KPb[dh][b] * 3 + KPb[dw][c]];
                    tot += lA3[p * 27 + dd * 9 + dh * 3 + dw] * sw;
                }
        for (int f = 0; f < 6; ++f) {
            const int s = f >> 1, c = (f & 1) ? 2 : 0;
            float fsum = 0.f;
            for (int du = 0; du < 3; ++du)
                for (int dv = 0; dv < 3; ++dv) {
                    float sw = 0.f;
                    for (int a = 0; a < KPn[du]; ++a)
                        for (int b = 0; b < KPn[dv]; ++b) {
                            const int ku = KPa[du][a], kup = KPb[du][a];
                            const int kv = KPa[dv][b], kvp = KPb[dv][b];
                            int ii, jj;
                            if (s == 0)      { ii = c * 9 + ku * 3 + kv;  jj = c * 9 + kup * 3 + kvp; }
                            else if (s == 1) { ii = ku * 9 + c * 3 + kv;  jj = kup * 9 + c * 3 + kvp; }
                            else             { ii = ku * 9 + kv * 3 + c;  jj = kup * 9 + kvp * 3 + c; }
                            sw += wi[ii] * wj[jj];
                        }
                    fsum += lA2[(f * 9 + p) * 9 + du * 3 + dv] * sw;
                }
            tot -= fsum;
        }
        for (int e12 = 0; e12 < 12; ++e12) {
            const int dp = e12 >> 2;
            const int c1 = ((e12 >> 1) & 1) ? 2 : 0, c2 = (e12 & 1) ? 2 : 0;
            float esum = 0.f;
            for (int dt = 0; dt < 3; ++dt) {
                float sw = 0.f;
                for (int a = 0; a < KPn[dt]; ++a) {
                    const int kt = KPa[dt][a], ktp = KPb[dt][a];
                    int ii, jj;
                    if (dp == 0)      { ii = c1 * 9 + c2 * 3 + kt; jj = c1 * 9 + c2 * 3 + ktp; }
                    else if (dp == 1) { ii = c1 * 9 + kt * 3 + c2; jj = c1 * 9 + ktp * 3 + c2; }
                    else              { ii = kt * 9 + c1 * 3 + c2; jj = ktp * 9 + c1 * 3 + c2; }
                    sw += wi[ii] * wj[jj];
                }
                esum += lA1[(e12 * 9 + p) * 3 + dt] * sw;
            }
            tot += esum;
        }
        for (int c = 0; c < 8; ++c) {
            const int kk = (((c >> 2) & 1) ? 2 : 0) * 9 +
                           (((c >> 1) & 1) ? 2 : 0) * 3 + ((c & 1) ? 2 : 0);
            tot -= lA0[c * 9 + p] * wi[kk] * wj[kk];
        }
        red2[tid] = tot;
    }
    if (tid >= 144 && tid < 192) {
        const int t = tid - 144, co = t / 3, ci = t % 3;
        const float* wi = lw + (ci * 16 + co) * 27;
        float lw3 = 0.f;
        for (int k = 0; k < 27; ++k) lw3 += wi[k];
        float tot = lX3[ci] * lw3;
        for (int f = 0; f < 6; ++f) {
            const int s = f >> 1, c = (f & 1) ? 2 : 0;
            float l2 = 0.f;
            for (int ku = 0; ku < 3; ++ku)
                for (int kv = 0; kv < 3; ++kv) {
                    const int ii = (s == 0) ? c * 9 + ku * 3 + kv
                                 : (s == 1) ? ku * 9 + c * 3 + kv
                                            : ku * 9 + kv * 3 + c;
                    l2 += wi[ii];
                }
            tot -= lX2[f * 3 + ci] * l2;
        }
        for (int e12 = 0; e12 < 12; ++e12) {
            const int dp = e12 >> 2;
            const int c1 = ((e12 >> 1) & 1) ? 2 : 0, c2 = (e12 & 1) ? 2 : 0;
            float l1 = 0.f;
            for (int kt = 0; kt < 3; ++kt) {
                const int ii = (dp == 0) ? c1 * 9 + c2 * 3 + kt
                             : (dp == 1) ? c1 * 9 + kt * 3 + c2
                                         : kt * 9 + c1 * 3 + c2;
                l1 += wi[ii];
            }
            tot += lX1[e12 * 3 + ci] * l1;
        }
        for (int c = 0; c < 8; ++c) {
            const int kk = (((c >> 2) & 1) ? 2 : 0) * 9 +
                           (((c >> 1) & 1) ? 2 : 0) * 3 + ((c & 1) ? 2 : 0);
            tot -= lX0[c * 3 + ci] * wi[kk];
        }
        red1[t] = tot;
    }
    __syncthreads();
    if (tid < 16) {
        float S2 = 0.f;
        for (int p = 0; p < 9; ++p) S2 += red2[tid * 9 + p];
        const float S1 = red1[tid * 3] + red1[tid * 3 + 1] + red1[tid * 3 + 2];
        const float mean = S1 / COUNT_Y;
        const float var = S2 / COUNT_Y - mean * mean;
        const float invg = rsqrtf(var + 1e-5f) * gamma[tid];
        ab[tid] = invg * (1.0f / 64.0f);
        ab[16 + tid] = beta[tid] - mean * invg;
    }
}

__global__ __launch_bounds__(256) void apply_norm(
    float* __restrict__ out, const float* __restrict__ ab) {
    const int base = (blockIdx.x * 256 + threadIdx.x) * 4;
    if (base >= TOTAL_OUT) return;
    float4 v = *reinterpret_cast<float4*>(out + base);
    float r[4] = {v.x, v.y, v.z, v.w};
    #pragma unroll
    for (int j = 0; j < 4; ++j) {
        const int c = ((base + j) / POOL3) & 15;
        r[j] = fmaf(r[j], ab[c], ab[16 + c]);
    }
    *reinterpret_cast<float4*>(out + base) = make_float4(r[0], r[1], r[2], r[3]);
}

extern "C" void kernel_launch(void* const* d_in, const int* in_sizes, int n_in,
                              void* d_out, int out_size, void* d_ws, size_t ws_size,
                              hipStream_t stream) {
    const float* x     = (const float*)d_in[0];
    const float* w     = (const float*)d_in[1];
    const float* gamma = (const float*)d_in[2];
    const float* beta  = (const float*)d_in[3];
    float* out = (float*)d_out;
    float* ws  = (float*)d_ws;

    mega_k<<<5772, 256, 0, stream>>>(x, w, ws + WS_A3P, ws + WS_X3P,
                                     ws + WS_A2P, ws + WS_X2P,
                                     ws + WS_A1, ws + WS_X1, out);
    reduce_A3<<<62, 256, 0, stream>>>(ws + WS_A3P, ws + WS_X3P, ws + WS_A3R);
    finalize2<<<1, 256, 0, stream>>>(x, w, gamma, beta, ws, ws + WS_AB);
    apply_norm<<<(TOTAL_OUT / 4 + 255) / 256, 256, 0, stream>>>(out, ws + WS_AB);
}

// Round 14
// 64.971 us; speedup vs baseline: 1.8501x; 1.8501x over previous
//
#include <hip/hip_runtime.h>

// ConvTranspose3d(3->16,k=3,s=2,p=1) + per-channel BN-norm + 2x avgpool2, fully fused.
// Identity 1: pooled output = stride-2 3^3 conv of x with collapsed kernel G (+norm inline).
// Identity 2: sum(y), sum(y^2) via x-autocorrelation at 27 lags + inclusion-exclusion
// boundary corrections (faces/edges/corners).
// R14 = R12 structure (best: 71.8us) with: register-staged unrolled staging (no
// per-iter vmcnt stalls), minimal zero-init, 2-barrier/pass 160-lane reduction,
// small blocks first in the grid. 4 launches.

#define I3 32768
#define NS 98304              // n stride in x = 3*32768
#define COUNT_Y 8001504.0f    // 32*63^3
#define POOL3 3375
#define TOTAL_OUT 1728000

// ws layout (floats)
#define WS_G    0        // 1296 (unused; G computed in pooled_norm path below)
#define WS_A3P  1296     // 512*162 = 82944 (symmetric pairs q*27+lag)
#define WS_X3P  84240    // 512*3   = 1536
#define WS_A2P  85776    // 486*32  = 15552
#define WS_X2P  101328   // 18*32   = 576
#define WS_A1   101904   // 324
#define WS_X1   102228   // 36
#define WS_A3R  102264   // 246 (ordered A3 [243] + X3 [3])
#define WS_AB   102510   // 32

// mega smem layout (floats)
#define SM_XS   0        // [3][6][34][16] = 9792
#define SM_HLO  9792     // [3][6][34] = 612
#define SM_HHI  10404    // 612
#define SM_RBUF 11016    // 256*20 = 5120
#define SM_RB2  16136    // 32*20 = 640
#define SM_REDA 16776    // 9*20 = 180
#define SM_REDX 16956    // 12
#define SM_TOT  16968    // 67,872 B -> 2 blocks/CU

__device__ __forceinline__ float4 add4(float4 a, float4 b) {
    return make_float4(a.x + b.x, a.y + b.y, a.z + b.z, a.w + b.w);
}

// ---------- mega: faces(192) + edges(12) + prep_G(6) + autocorr(512) ----------
__global__ __launch_bounds__(256, 2) void mega_k(
    const float* __restrict__ x, const float* __restrict__ w,
    float* __restrict__ A3p, float* __restrict__ X3p,
    float* __restrict__ A2P, float* __restrict__ X2P,
    float* __restrict__ A1, float* __restrict__ X1,
    float* __restrict__ G)
{
    const int b = blockIdx.x;
    const int tid = threadIdx.x;
    __shared__ float smem[SM_TOT];

    #define PL(ci,u,v) smem[((ci)*32+(u))*33+(v)]
    if (b < 192) {
        // ======== faces ========
        const int f = b >> 5, n = b & 31;
        const int s = f >> 1, e = (f & 1) ? 31 : 0;
        int su, sv, off;
        if (s == 0)      { su = 32;   sv = 1;  off = e * 1024; }
        else if (s == 1) { su = 1024; sv = 1;  off = e * 32;   }
        else             { su = 1024; sv = 32; off = e;        }
        const float* xb = x + (size_t)n * NS + off;
        for (int idx = tid; idx < 3072; idx += 256) {
            const int ci = idx >> 10, r = idx & 1023, u = r >> 5, v = r & 31;
            PL(ci, u, v) = xb[ci * I3 + u * su + v * sv];
        }
        __syncthreads();
        const int grp = tid >> 5, u = tid & 31;
        #pragma unroll 1
        for (int j = grp; j < 84; j += 8) {
            float t2 = 0.f;
            if (j < 81) {
                const int p = j / 9, lag = j % 9;
                const int du = lag / 3 - 1, dv = lag % 3 - 1;
                const int ci = p / 3, cj = p % 3;
                const int un = u + du;
                if ((unsigned)un < 32u) {
                    const int vlo = (dv == -1) ? 1 : 0, vhi = (dv == 1) ? 30 : 31;
                    const float* ro = &PL(ci, u, 0);
                    const float* rn = &PL(cj, un, dv);
                    for (int v = vlo; v <= vhi; ++v) t2 = fmaf(ro[v], rn[v], t2);
                }
            } else {
                const int ci = j - 81;
                for (int v = 0; v < 32; ++v) t2 += PL(ci, u, v);
            }
            #pragma unroll
            for (int m = 1; m < 32; m <<= 1) t2 += __shfl_xor(t2, m, 32);
            if (u == 0) {
                if (j < 81) A2P[(f * 81 + j) * 32 + n] = t2;
                else        X2P[(f * 3 + (j - 81)) * 32 + n] = t2;
            }
        }
        return;
    }

    if (b < 204) {
        // ======== edges ========
        const int e12 = b - 192;
        const int dp = e12 >> 2;
        const int e1 = ((e12 >> 1) & 1) ? 31 : 0, e2 = (e12 & 1) ? 31 : 0;
        int st, off;
        if (dp == 0)      { st = 1;    off = e1 * 1024 + e2 * 32; }
        else if (dp == 1) { st = 32;   off = e1 * 1024 + e2;      }
        else              { st = 1024; off = e1 * 32 + e2;        }
        for (int idx = tid; idx < 3072; idx += 256) {
            const int ci = idx >> 10, r = idx & 1023, n = r >> 5, v = r & 31;
            PL(ci, n, v) = x[(size_t)n * NS + ci * I3 + off + v * st];
        }
        __syncthreads();
        const int grp = tid >> 5, n2 = tid & 31;
        #pragma unroll 1
        for (int j = grp; j < 30; j += 8) {
            float t = 0.f;
            if (j < 27) {
                const int p = j / 3, dt = j % 3 - 1;
                const int ci = p / 3, cj = p % 3;
                const int vlo = (dt == -1) ? 1 : 0, vhi = (dt == 1) ? 30 : 31;
                const float* ro = &PL(ci, n2, 0);
                const float* rn = &PL(cj, n2, dt);
                for (int v = vlo; v <= vhi; ++v) t = fmaf(ro[v], rn[v], t);
            } else {
                const int ci = j - 27;
                for (int v = 0; v < 32; ++v) t += PL(ci, n2, v);
            }
            #pragma unroll
            for (int m = 1; m < 32; m <<= 1) t += __shfl_xor(t, m, 32);
            if (n2 == 0) {
                if (j < 27) A1[e12 * 27 + j] = t;
                else        X1[e12 * 3 + (j - 27)] = t;
            }
        }
        return;
    }

    if (b < 210) {
        // ======== prep_G ========
        const int idx = (b - 204) * 256 + tid;
        if (idx >= 1296) return;
        const int ci = idx / 432, rem = idx % 432, co = rem / 27, j = rem % 27;
        const int jd = j / 9, jh = (j / 3) % 3, jw = j % 3;
        const int SLEN[3] = {2, 3, 1};
        const int SK[3][3] = {{1, 2, 0}, {0, 1, 2}, {0, 0, 0}};
        const float* wp = w + (ci * 16 + co) * 27;
        float s = 0.f;
        for (int a = 0; a < SLEN[jd]; ++a)
            for (int bq = 0; bq < SLEN[jh]; ++bq)
                for (int c = 0; c < SLEN[jw]; ++c)
                    s += wp[SK[jd][a] * 9 + SK[jh][bq] * 3 + SK[jw][c]];
        G[idx] = s;
        return;
    }

    // ======== 3D autocorrelation, symmetric pairs, (n, d-slab, w-half) ========
    {
        const int ab_ = b - 210;            // 0..511
        const int bx = ab_ >> 5, n = ab_ & 31;
        const int dblk = bx >> 1, whalf = bx & 1;
        const int d0 = dblk * 4, w0 = whalf * 16;
        const int dsub = tid >> 7;          // 0..1 (pair of d-planes)
        const int h    = (tid >> 2) & 31;
        const int w4   = tid & 3;           // 4-float chunk in 16-wide half
        const int wave = tid >> 6, lane = tid & 63;

        #define XS(ci,dp,hh,ww)  smem[SM_XS + (((ci)*6+(dp))*34+(hh))*16+(ww)]
        #define HLO(ci,dp,hh)    smem[SM_HLO + ((ci)*6+(dp))*34+(hh)]
        #define HHI(ci,dp,hh)    smem[SM_HHI + ((ci)*6+(dp))*34+(hh)]

        // minimal zero-init: xs rows 0/33 (576) + halo rows 0/33 (72)
        for (int i = tid; i < 576; i += 256) {
            const int cp = i >> 5, r = i & 31;
            const int row = (r < 16) ? 0 : 33, ww = r & 15;
            smem[SM_XS + (cp * 34 + row) * 16 + ww] = 0.f;
        }
        if (tid < 72) {
            const int arr = tid / 36, r = tid % 36, cp = r >> 1;
            const int row = (r & 1) ? 33 : 0;
            smem[SM_HLO + arr * 612 + cp * 34 + row] = 0.f;
        }

        // register-staged main load: 9 float4 per thread, all in flight
        float4 st[9];
        #pragma unroll
        for (int k = 0; k < 9; ++k) {
            const int i = tid + k * 256;
            const int c4 = i & 3, hh = (i >> 2) & 31, cp = i >> 7;
            const int dp = cp % 6, ci = cp / 6;
            const int d = d0 - 1 + dp;
            const bool v = ((unsigned)d < 32u);
            const int dc = v ? d : 0;
            const float4 f = *reinterpret_cast<const float4*>(
                x + (size_t)n * NS + ci * I3 + dc * 1024 + hh * 32 + w0 + c4 * 4);
            st[k] = v ? f : make_float4(0.f, 0.f, 0.f, 0.f);
        }
        // register-staged halo load: 5 scalars per thread (last partially masked)
        float hv[5];
        #pragma unroll
        for (int k = 0; k < 5; ++k) {
            const int i = tid + k * 256;
            const int side = i & 1, hh = (i >> 1) & 31;
            const int cp = min(i >> 6, 17);
            const int dp = cp % 6, ci = cp / 6;
            const int d = d0 - 1 + dp;
            const int gw = side ? (w0 + 16) : (w0 - 1);
            const bool v = (i < 1152) && ((unsigned)d < 32u) && ((unsigned)gw < 32u);
            const int dc = ((unsigned)d < 32u) ? d : 0;
            const int gwc = min(max(gw, 0), 31);
            const float f = x[(size_t)n * NS + ci * I3 + dc * 1024 + hh * 32 + gwc];
            hv[k] = v ? f : 0.f;
        }
        #pragma unroll
        for (int k = 0; k < 9; ++k) {
            const int i = tid + k * 256;
            const int c4 = i & 3, hh = (i >> 2) & 31, cp = i >> 7;
            const int dp = cp % 6, ci = cp / 6;
            *reinterpret_cast<float4*>(&XS(ci, dp, hh + 1, c4 * 4)) = st[k];
        }
        #pragma unroll
        for (int k = 0; k < 5; ++k) {
            const int i = tid + k * 256;
            if (i < 1152) {
                const int side = i & 1, hh = (i >> 1) & 31, cp = i >> 6;
                if (side) smem[SM_HHI + cp * 34 + hh + 1] = hv[k];
                else      smem[SM_HLO + cp * 34 + hh + 1] = hv[k];
            }
        }
        __syncthreads();

        // hoisted ov loads (both dl) and X sums
        float4 ov[2][3];
        #pragma unroll
        for (int dl = 0; dl < 2; ++dl) {
            const int dp = 1 + dsub * 2 + dl;
            #pragma unroll
            for (int ci = 0; ci < 3; ++ci)
                ov[dl][ci] = *reinterpret_cast<const float4*>(&XS(ci, dp, h + 1, w4 * 4));
        }
        float sx[3];
        #pragma unroll
        for (int ci = 0; ci < 3; ++ci)
            sx[ci] = ov[0][ci].x + ov[0][ci].y + ov[0][ci].z + ov[0][ci].w +
                     ov[1][ci].x + ov[1][ci].y + ov[1][ci].z + ov[1][ci].w;
        #pragma unroll
        for (int m = 1; m < 64; m <<= 1) {
            sx[0] += __shfl_xor(sx[0], m, 64);
            sx[1] += __shfl_xor(sx[1], m, 64);
            sx[2] += __shfl_xor(sx[2], m, 64);
        }
        if (lane == 0) {
            smem[SM_REDX + wave * 3 + 0] = sx[0];
            smem[SM_REDX + wave * 3 + 1] = sx[1];
            smem[SM_REDX + wave * 3 + 2] = sx[2];
        }

        #pragma unroll 1
        for (int ddh = 0; ddh < 9; ++ddh) {
            const int dd = ddh / 3 - 1, dh = ddh % 3 - 1;
            float acc[18];
            #pragma unroll
            for (int j = 0; j < 18; ++j) acc[j] = 0.f;

            #pragma unroll
            for (int dl = 0; dl < 2; ++dl) {
                const int dp = 1 + dsub * 2 + dl;
                const int dpn = dp + dd, hn = h + 1 + dh;
                #pragma unroll
                for (int cj = 0; cj < 3; ++cj) {
                    const float4 bv = *reinterpret_cast<const float4*>(&XS(cj, dpn, hn, w4 * 4));
                    float nxt = __shfl(bv.x, lane + 1, 64);
                    float prv = __shfl(bv.w, lane - 1, 64);
                    if (w4 == 3) nxt = HHI(cj, dpn, hn);
                    if (w4 == 0) prv = HLO(cj, dpn, hn);
                    #pragma unroll
                    for (int ci = 0; ci <= cj; ++ci) {
                        const int q = (cj == 0) ? 0 : (cj == 1 ? (ci == 0 ? 1 : 3)
                                                                : (ci == 0 ? 2 : (ci == 1 ? 4 : 5)));
                        const int p3 = q * 3;
                        const float4 o = ov[dl][ci];
                        acc[p3 + 0] = fmaf(o.x, prv,  acc[p3 + 0]);
                        acc[p3 + 0] = fmaf(o.y, bv.x, acc[p3 + 0]);
                        acc[p3 + 0] = fmaf(o.z, bv.y, acc[p3 + 0]);
                        acc[p3 + 0] = fmaf(o.w, bv.z, acc[p3 + 0]);
                        acc[p3 + 1] = fmaf(o.x, bv.x, acc[p3 + 1]);
                        acc[p3 + 1] = fmaf(o.y, bv.y, acc[p3 + 1]);
                        acc[p3 + 1] = fmaf(o.z, bv.z, acc[p3 + 1]);
                        acc[p3 + 1] = fmaf(o.w, bv.w, acc[p3 + 1]);
                        acc[p3 + 2] = fmaf(o.x, bv.y, acc[p3 + 2]);
                        acc[p3 + 2] = fmaf(o.y, bv.z, acc[p3 + 2]);
                        acc[p3 + 2] = fmaf(o.z, bv.w, acc[p3 + 2]);
                        acc[p3 + 2] = fmaf(o.w, nxt,  acc[p3 + 2]);
                    }
                }
            }

            // rbuf write (b128 x5)
            {
                float4* rb = reinterpret_cast<float4*>(&smem[SM_RBUF + tid * 20]);
                rb[0] = make_float4(acc[0],  acc[1],  acc[2],  acc[3]);
                rb[1] = make_float4(acc[4],  acc[5],  acc[6],  acc[7]);
                rb[2] = make_float4(acc[8],  acc[9],  acc[10], acc[11]);
                rb[3] = make_float4(acc[12], acc[13], acc[14], acc[15]);
                rb[4] = make_float4(acc[16], acc[17], 0.f, 0.f);
            }
            __syncthreads();             // A: rbuf visible; prev pass stage2 done
            if (tid < 160) {             // stage1: 160 lanes x 8 b128 reads
                const int j4 = tid % 5, rblk = tid / 5;
                float4 s = make_float4(0.f, 0.f, 0.f, 0.f);
                #pragma unroll
                for (int k = 0; k < 8; ++k) {
                    const int r = rblk * 8 + k;
                    s = add4(s, *reinterpret_cast<const float4*>(&smem[SM_RBUF + r * 20 + j4 * 4]));
                }
                *reinterpret_cast<float4*>(&smem[SM_RB2 + rblk * 20 + j4 * 4]) = s;
            }
            __syncthreads();             // B: RB2 visible (next rbuf write is WAR-safe)
            if (tid < 18) {              // stage2: 18 lanes x 32 b32 reads
                float s = 0.f;
                #pragma unroll
                for (int r = 0; r < 32; ++r) s += smem[SM_RB2 + r * 20 + tid];
                smem[SM_REDA + ddh * 20 + tid] = s;
            }
        }
        __syncthreads();

        if (tid < 162) {
            const int q = tid / 27, rem = tid % 27;
            const int pass = rem / 3, dw = rem % 3;
            A3p[(size_t)ab_ * 162 + tid] = smem[SM_REDA + pass * 20 + q * 3 + dw];
        } else if (tid < 165) {
            const int ci = tid - 162;
            X3p[ab_ * 3 + ci] = smem[SM_REDX + ci] + smem[SM_REDX + 3 + ci] +
                                smem[SM_REDX + 6 + ci] + smem[SM_REDX + 9 + ci];
        }
    }
}

// ---------- reduce + expand symmetric A3 -> ordered 243 (+ X3) ----------
__global__ __launch_bounds__(256) void reduce_A3(
    const float* __restrict__ A3p, const float* __restrict__ X3p,
    float* __restrict__ A3r) {
    const int wv = blockIdx.x * 4 + (threadIdx.x >> 6);  // 0..247
    const int lane = threadIdx.x & 63;
    float s = 0.f;
    if (wv < 243) {
        const int p = wv / 27, lag = wv % 27;
        const int ci = p / 3, cj = p % 3;
        int q, l2;
        if (ci <= cj) {
            q = (ci == 0) ? cj : (ci == 1 ? 2 + cj : 5);
            l2 = lag;
        } else {
            q = (cj == 0) ? ci : 4;
            l2 = 26 - lag;
        }
        #pragma unroll
        for (int k = 0; k < 8; ++k)
            s += A3p[(size_t)(lane * 8 + k) * 162 + q * 27 + l2];
    } else if (wv < 246) {
        const int ci = wv - 243;
        #pragma unroll
        for (int k = 0; k < 8; ++k) s += X3p[(lane * 8 + k) * 3 + ci];
    }
    #pragma unroll
    for (int m = 1; m < 64; m <<= 1) s += __shfl_xor(s, m, 64);
    if (lane == 0 && wv < 246) A3r[wv] = s;
}

// ---------- finalize: combine A's with weight-pair sums -> ab ----------
__global__ __launch_bounds__(256) void finalize2(
    const float* __restrict__ x, const float* __restrict__ w,
    const float* __restrict__ gamma, const float* __restrict__ beta,
    const float* __restrict__ ws, float* __restrict__ ab) {
    const int tid = threadIdx.x;
    __shared__ float lw[1296];
    __shared__ float lA3[243], lX3[3], lA2[486], lX2[18], lA1[324], lX1[36];
    __shared__ float lxc[8][3][32];
    __shared__ float lA0[72], lX0[24];
    __shared__ float red2[144], red1[48];

    for (int i = tid; i < 1296; i += 256) lw[i] = w[i];
    if (tid < 243) lA3[tid] = ws[WS_A3R + tid];
    if (tid >= 243 && tid < 246) lX3[tid - 243] = ws[WS_A3R + tid];
    for (int i = tid; i < 486; i += 256) {
        const float* p = ws + WS_A2P + i * 32;
        float s = 0.f;
        #pragma unroll
        for (int nn = 0; nn < 32; ++nn) s += p[nn];
        lA2[i] = s;
    }
    if (tid < 18) {
        const float* p = ws + WS_X2P + tid * 32;
        float s = 0.f;
        for (int nn = 0; nn < 32; ++nn) s += p[nn];
        lX2[tid] = s;
    }
    for (int i = tid; i < 324; i += 256) lA1[i] = ws[WS_A1 + i];
    if (tid < 36) lX1[tid] = ws[WS_X1 + tid];
    for (int i = tid; i < 768; i += 256) {
        const int c = i / 96, ci = (i / 32) % 3, nn = i % 32;
        const int off = (((c >> 2) & 1) ? 31 : 0) * 1024 +
                        (((c >> 1) & 1) ? 31 : 0) * 32 + ((c & 1) ? 31 : 0);
        lxc[c][ci][nn] = x[(size_t)nn * NS + ci * I3 + off];
    }
    __syncthreads();
    if (tid < 72) {
        const int c = tid / 9, p = tid % 9, ci = p / 3, cj = p % 3;
        float s = 0.f;
        for (int nn = 0; nn < 32; ++nn) s += lxc[c][ci][nn] * lxc[c][cj][nn];
        lA0[tid] = s;
    }
    if (tid >= 72 && tid < 96) {
        const int t = tid - 72, c = t / 3, ci = t % 3;
        float s = 0.f;
        for (int nn = 0; nn < 32; ++nn) s += lxc[c][ci][nn];
        lX0[t] = s;
    }
    __syncthreads();

    const int KPn[3] = {1, 3, 1};
    const int KPa[3][3] = {{0, 0, 0}, {0, 1, 2}, {2, 0, 0}};
    const int KPb[3][3] = {{2, 0, 0}, {0, 1, 2}, {0, 0, 0}};

    if (tid < 144) {
        const int co = tid / 9, p = tid % 9, ci = p / 3, cj = p % 3;
        const float* wi = lw + (ci * 16 + co) * 27;
        const float* wj = lw + (cj * 16 + co) * 27;
        float tot = 0.f;
        for (int dd = 0; dd < 3; ++dd)
            for (int dh = 0; dh < 3; ++dh)
                for (int dw = 0; dw < 3; ++dw) {
                    float sw = 0.f;
                    for (int a = 0; a < KPn[dd]; ++a)
                        for (int b = 0; b < KPn[dh]; ++b)
                            for (int c = 0; c < KPn[dw]; ++c)
                                sw += wi[KPa[dd][a] * 9 + KPa[dh][b] * 3 + KPa[dw][c]] *
                                      wj[KPb[dd][a] * 9 + KPb[dh][b] * 3 + KPb[dw][c]];
                    tot += lA3[p * 27 + dd * 9 + dh * 3 + dw] * sw;
                }
        for (int f = 0; f < 6; ++f) {
            const int s = f >> 1, c = (f & 1) ? 2 : 0;
            float fsum = 0.f;
            for (int du = 0; du < 3; ++du)
                for (int dv = 0; dv < 3; ++dv) {
                    float sw = 0.f;
                    for (int a = 0; a < KPn[du]; ++a)
                        for (int b = 0; b < KPn[dv]; ++b) {
                            const int ku = KPa[du][a], kup = KPb[du][a];
                            const int kv = KPa[dv][b], kvp = KPb[dv][b];
                            int ii, jj;
                            if (s == 0)      { ii = c * 9 + ku * 3 + kv;  jj = c * 9 + kup * 3 + kvp; }
                            else if (s == 1) { ii = ku * 9 + c * 3 + kv;  jj = kup * 9 + c * 3 + kvp; }
                            else             { ii = ku * 9 + kv * 3 + c;  jj = kup * 9 + kvp * 3 + c; }
                            sw += wi[ii] * wj[jj];
                        }
                    fsum += lA2[(f * 9 + p) * 9 + du * 3 + dv] * sw;
                }
            tot -= fsum;
        }
        for (int e12 = 0; e12 < 12; ++e12) {
            const int dp = e12 >> 2;
            const int c1 = ((e12 >> 1) & 1) ? 2 : 0, c2 = (e12 & 1) ? 2 : 0;
            float esum = 0.f;
            for (int dt = 0; dt < 3; ++dt) {
                float sw = 0.f;
                for (int a = 0; a < KPn[dt]; ++a) {
                    const int kt = KPa[dt][a], ktp = KPb[dt][a];
                    int ii, jj;
                    if (dp == 0)      { ii = c1 * 9 + c2 * 3 + kt; jj = c1 * 9 + c2 * 3 + ktp; }
                    else if (dp == 1) { ii = c1 * 9 + kt * 3 + c2; jj = c1 * 9 + ktp * 3 + c2; }
                    else              { ii = kt * 9 + c1 * 3 + c2; jj = ktp * 9 + c1 * 3 + c2; }
                    sw += wi[ii] * wj[jj];
                }
                esum += lA1[(e12 * 9 + p) * 3 + dt] * sw;
            }
            tot += esum;
        }
        for (int c = 0; c < 8; ++c) {
            const int kk = (((c >> 2) & 1) ? 2 : 0) * 9 +
                           (((c >> 1) & 1) ? 2 : 0) * 3 + ((c & 1) ? 2 : 0);
            tot -= lA0[c * 9 + p] * wi[kk] * wj[kk];
        }
        red2[tid] = tot;
    }
    if (tid >= 144 && tid < 192) {
        const int t = tid - 144, co = t / 3, ci = t % 3;
        const float* wi = lw + (ci * 16 + co) * 27;
        float lw3 = 0.f;
        for (int k = 0; k < 27; ++k) lw3 += wi[k];
        float tot = lX3[ci] * lw3;
        for (int f = 0; f < 6; ++f) {
            const int s = f >> 1, c = (f & 1) ? 2 : 0;
            float l2 = 0.f;
            for (int ku = 0; ku < 3; ++ku)
                for (int kv = 0; kv < 3; ++kv) {
                    const int ii = (s == 0) ? c * 9 + ku * 3 + kv
                                 : (s == 1) ? ku * 9 + c * 3 + kv
                                            : ku * 9 + kv * 3 + c;
                    l2 += wi[ii];
                }
            tot -= lX2[f * 3 + ci] * l2;
        }
        for (int e12 = 0; e12 < 12; ++e12) {
            const int dp = e12 >> 2;
            const int c1 = ((e12 >> 1) & 1) ? 2 : 0, c2 = (e12 & 1) ? 2 : 0;
            float l1 = 0.f;
            for (int kt = 0; kt < 3; ++kt) {
                const int ii = (dp == 0) ? c1 * 9 + c2 * 3 + kt
                             : (dp == 1) ? c1 * 9 + kt * 3 + c2
                                         : kt * 9 + c1 * 3 + c2;
                l1 += wi[ii];
            }
            tot += lX1[e12 * 3 + ci] * l1;
        }
        for (int c = 0; c < 8; ++c) {
            const int kk = (((c >> 2) & 1) ? 2 : 0) * 9 +
                           (((c >> 1) & 1) ? 2 : 0) * 3 + ((c & 1) ? 2 : 0);
            tot -= lX0[c * 3 + ci] * wi[kk];
        }
        red1[t] = tot;
    }
    __syncthreads();
    if (tid < 16) {
        float S2 = 0.f;
        for (int p = 0; p < 9; ++p) S2 += red2[tid * 9 + p];
        const float S1 = red1[tid * 3] + red1[tid * 3 + 1] + red1[tid * 3 + 2];
        const float mean = S1 / COUNT_Y;
        const float var = S2 / COUNT_Y - mean * mean;
        const float invg = rsqrtf(var + 1e-5f) * gamma[tid];
        ab[tid] = invg * (1.0f / 64.0f);
        ab[16 + tid] = beta[tid] - mean * invg;
    }
}

// ---------- pooled conv + norm (runs last) ----------
__global__ __launch_bounds__(256, 4) void pooled_norm(
    const float* __restrict__ x, const float* __restrict__ G,
    const float* __restrict__ ab, float* __restrict__ out) {
    const int pd = blockIdx.x >> 1, coh = blockIdx.x & 1, n = blockIdx.y;
    const int tid = threadIdx.x;
    if (tid >= 225) return;
    const int ph = tid / 15, pw = tid % 15;
    const float* xn = x + (size_t)n * NS;
    float acc[8] = {};
    #pragma unroll
    for (int ci = 0; ci < 3; ++ci) {
        float xl[27];
        const float* xc = xn + ci * I3 + (2 * pd) * 1024 + (2 * ph) * 32 + 2 * pw;
        #pragma unroll
        for (int jd = 0; jd < 3; ++jd)
            #pragma unroll
            for (int jh = 0; jh < 3; ++jh) {
                const float* r = xc + jd * 1024 + jh * 32;
                const float2 f2 = *reinterpret_cast<const float2*>(r);
                xl[jd * 9 + jh * 3 + 0] = f2.x;
                xl[jd * 9 + jh * 3 + 1] = f2.y;
                xl[jd * 9 + jh * 3 + 2] = r[2];
            }
        #pragma unroll
        for (int c8 = 0; c8 < 8; ++c8) {
            const float* gp = G + (ci * 16 + coh * 8 + c8) * 27;
            #pragma unroll
            for (int j = 0; j < 27; ++j)
                acc[c8] = fmaf(gp[j], xl[j], acc[c8]);
        }
    }
    const int ob = (n * 16 + coh * 8) * POOL3 + pd * 225 + ph * 15 + pw;
    #pragma unroll
    for (int c8 = 0; c8 < 8; ++c8) {
        const int co = coh * 8 + c8;
        out[ob + c8 * POOL3] = fmaf(acc[c8], ab[co], ab[16 + co]);
    }
}

extern "C" void kernel_launch(void* const* d_in, const int* in_sizes, int n_in,
                              void* d_out, int out_size, void* d_ws, size_t ws_size,
                              hipStream_t stream) {
    const float* x     = (const float*)d_in[0];
    const float* w     = (const float*)d_in[1];
    const float* gamma = (const float*)d_in[2];
    const float* beta  = (const float*)d_in[3];
    float* out = (float*)d_out;
    float* ws  = (float*)d_ws;

    mega_k<<<722, 256, 0, stream>>>(x, w, ws + WS_A3P, ws + WS_X3P,
                                    ws + WS_A2P, ws + WS_X2P,
                                    ws + WS_A1, ws + WS_X1, ws + WS_G);
    reduce_A3<<<62, 256, 0, stream>>>(ws + WS_A3P, ws + WS_X3P, ws + WS_A3R);
    finalize2<<<1, 256, 0, stream>>>(x, w, gamma, beta, ws, ws + WS_AB);
    pooled_norm<<<dim3(30, 32), 256, 0, stream>>>(x, ws + WS_G, ws + WS_AB, out);
}